// Round 1
// baseline (728.516 us; speedup 1.0000x reference)
//
#include <hip/hip_runtime.h>
#include <hip/hip_bf16.h>

#define NN 20000
#define EE 320000
#define LGN 4

typedef unsigned short u16;
typedef short bf16x8 __attribute__((ext_vector_type(8)));
typedef float f32x4 __attribute__((ext_vector_type(4)));

__device__ __forceinline__ float bf2f(u16 v) {
    unsigned int u = ((unsigned int)v) << 16;
    float f; __builtin_memcpy(&f, &u, 4); return f;
}
__device__ __forceinline__ u16 f2bf(float f) {
    __hip_bfloat16 h = __float2bfloat16(f);
    u16 u; __builtin_memcpy(&u, &h, 2); return u;
}

// ---- pass 1: degree (by source), col histogram, ew copy-out ----
__global__ __launch_bounds__(256) void k_edge1(const int* __restrict__ ei,
                                               const float* __restrict__ ew,
                                               float* __restrict__ deg,
                                               int* __restrict__ counts,
                                               float* __restrict__ out_ew) {
    int e = blockIdx.x * 256 + threadIdx.x;
    if (e >= EE) return;
    int r = ei[e];
    float w = ew[e];
    atomicAdd(&deg[r], w);
    atomicAdd(&counts[ei[EE + e]], 1);
    out_ew[e] = w;
}

__global__ __launch_bounds__(256) void k_rsqrt(float* __restrict__ deg) {
    int i = blockIdx.x * 256 + threadIdx.x;
    if (i >= NN) return;
    float d = deg[i];
    deg[i] = (d > 0.f) ? rsqrtf(d) : 0.f;
}

// ---- exclusive scan of col histogram (single block) ----
__global__ __launch_bounds__(1024) void k_scan(const int* __restrict__ counts,
                                               int* __restrict__ offs) {
    __shared__ int part[1024];
    int t = threadIdx.x;
    const int C = (NN + 1023) / 1024;  // 20
    int lo = t * C, hi = min(lo + C, NN);
    int s = 0;
    for (int i = lo; i < hi; i++) s += counts[i];
    part[t] = s;
    __syncthreads();
    for (int off = 1; off < 1024; off <<= 1) {
        int add = (t >= off) ? part[t - off] : 0;
        __syncthreads();
        part[t] += add;
        __syncthreads();
    }
    int base = part[t] - s;
    for (int i = lo; i < hi; i++) { offs[i] = base; base += counts[i]; }
    if (t == 1023) offs[NN] = part[1023];
}

// ---- pass 2: compute norm, scatter into CSR slots ----
__global__ __launch_bounds__(256) void k_scatter(const int* __restrict__ ei,
                                                 const float* __restrict__ ew,
                                                 const float* __restrict__ dis,
                                                 const int* __restrict__ offs,
                                                 int* __restrict__ cursor,
                                                 int* __restrict__ srow,
                                                 float* __restrict__ snorm) {
    int e = blockIdx.x * 256 + threadIdx.x;
    if (e >= EE) return;
    int r = ei[e], c = ei[EE + e];
    float nm = -(dis[r] * ew[e] * dis[c]);
    int pidx = offs[c] + atomicAdd(&cursor[c], 1);
    srow[pidx] = r;
    snorm[pidx] = nm;
}

// ---- f32 -> bf16 cast ----
__global__ __launch_bounds__(256) void k_cast(const float* __restrict__ src,
                                              u16* __restrict__ dst, int n) {
    int i = blockIdx.x * 256 + threadIdx.x;
    if (i < n) dst[i] = f2bf(src[i]);
}

// ---- fold BN affine: s = gamma*rsqrt(var+eps), t = beta - mean*s ----
__global__ __launch_bounds__(256) void k_foldbn(const float* __restrict__ g,
                                                const float* __restrict__ be,
                                                const float* __restrict__ mn,
                                                const float* __restrict__ vr,
                                                float* __restrict__ sc,
                                                float* __restrict__ sh) {
    int t = threadIdx.x;
    if (t < 256) {
        float s = g[t] * rsqrtf(vr[t] + 1e-5f);
        sc[t] = s;
        sh[t] = be[t] - mn[t] * s;
    }
}

// ---- CSR SpMM: out[c,:] = (dotx2 ? 2*S.x - xsub : S.x), bf16 in/out ----
__global__ __launch_bounds__(256) void k_prop(const u16* __restrict__ x, int ldx,
                                              const u16* __restrict__ xsub, int ldsub,
                                              int dotx2,
                                              u16* __restrict__ out, int ldo,
                                              const int* __restrict__ offs,
                                              const int* __restrict__ srow,
                                              const float* __restrict__ snorm) {
    int c = blockIdx.x, d = threadIdx.x;
    __shared__ int rb[256];
    __shared__ float wb[256];
    int s = offs[c], e = offs[c + 1];
    float acc = 0.f;
    for (int base = s; base < e; base += 256) {
        int cnt = min(256, e - base);
        if (d < cnt) { rb[d] = srow[base + d]; wb[d] = snorm[base + d]; }
        __syncthreads();
        for (int i = 0; i < cnt; i++)
            acc += wb[i] * bf2f(x[(size_t)rb[i] * ldx + d]);
        __syncthreads();
    }
    float r = acc;
    if (dotx2) r = 2.f * acc - bf2f(xsub[(size_t)c * ldsub + d]);
    out[(size_t)c * ldo + d] = f2bf(r);
}

// ---- bf16 MFMA GEMM: C[m,n] = A[m,:] @ B[:,n]; A split in 256-col chunks ----
// mode 0: relu -> bf16 outb (stride ldob)
// mode 1: +bias, relu, *sc + sh -> f32 outf (stride 256)
__global__ __launch_bounds__(256) void k_gemm(
    const u16* __restrict__ A0, const u16* __restrict__ A1,
    const u16* __restrict__ A2, const u16* __restrict__ A3,
    int lda0, int lda1, int lda2, int lda3,
    int K, const u16* __restrict__ B,
    int mode,
    u16* __restrict__ outb, int ldob,
    float* __restrict__ outf,
    const float* __restrict__ bias, const float* __restrict__ sc,
    const float* __restrict__ sh) {
    const u16* Ap[4] = {A0, A1, A2, A3};
    int lda[4] = {lda0, lda1, lda2, lda3};
    __shared__ __align__(16) short As[64][40];
    __shared__ __align__(16) short Bs[64][40];  // transposed: [n][k]
    int t = threadIdx.x;
    int m0 = blockIdx.x * 64;
    int n0 = blockIdx.y * 64;
    int wave = t >> 6, lane = t & 63, quad = lane >> 4, l16 = lane & 15;
    f32x4 acc[4] = {};
    int arow = t >> 2, akoff = (t & 3) * 8;
    int bk = t >> 3, bnoff = (t & 7) * 8;

    for (int kt = 0; kt < K; kt += 32) {
        // stage A tile (64 rows x 32 k)
        uint4 av = make_uint4(0u, 0u, 0u, 0u);
        int m = m0 + arow;
        if (m < NN) {
            int kg = kt + akoff;
            int ch = kg >> 8;
            const u16* ap = Ap[ch] + (size_t)m * lda[ch] + (kg & 255);
            av = *(const uint4*)ap;
        }
        *(uint4*)&As[arow][akoff] = av;
        // stage B tile (32 k x 64 n), transposed into Bs[n][k]
        const u16* bp = B + (size_t)(kt + bk) * 256 + (n0 + bnoff);
        uint4 bv = *(const uint4*)bp;
        u16 bvals[8];
        __builtin_memcpy(bvals, &bv, 16);
#pragma unroll
        for (int j = 0; j < 8; j++) Bs[bnoff + j][bk] = (short)bvals[j];
        __syncthreads();

        bf16x8 a = *(const bf16x8*)&As[wave * 16 + l16][quad * 8];
#pragma unroll
        for (int nt = 0; nt < 4; nt++) {
            bf16x8 b = *(const bf16x8*)&Bs[nt * 16 + l16][quad * 8];
            acc[nt] = __builtin_amdgcn_mfma_f32_16x16x32_bf16(a, b, acc[nt], 0, 0, 0);
        }
        __syncthreads();
    }

#pragma unroll
    for (int nt = 0; nt < 4; nt++) {
        int col = n0 + nt * 16 + l16;
#pragma unroll
        for (int i = 0; i < 4; i++) {
            int row = m0 + wave * 16 + quad * 4 + i;
            if (row >= NN) continue;
            float v = acc[nt][i];
            if (mode == 0) {
                v = v > 0.f ? v : 0.f;
                outb[(size_t)row * ldob + col] = f2bf(v);
            } else {
                v += bias[col];
                v = v > 0.f ? v : 0.f;
                v = v * sc[col] + sh[col];
                outf[(size_t)row * 256 + col] = v;
            }
        }
    }
}

// ---- final projection: logit[n,k] = z[n,:] @ w2[:,k] + b2[k], one wave/node ----
__global__ __launch_bounds__(256) void k_final(const float* __restrict__ z,
                                               const float* __restrict__ w2,
                                               const float* __restrict__ b2,
                                               float* __restrict__ out) {
    int wave = threadIdx.x >> 6, lane = threadIdx.x & 63;
    int n = blockIdx.x * 4 + wave;
    if (n >= NN) return;
    const float* zr = z + (size_t)n * 256;
    int j = lane * 4;
    float4 zv = *(const float4*)(zr + j);
    float4 wa = *(const float4*)(w2 + j * 2);
    float4 wb = *(const float4*)(w2 + j * 2 + 4);
    float a0 = zv.x * wa.x + zv.y * wa.z + zv.z * wb.x + zv.w * wb.z;
    float a1 = zv.x * wa.y + zv.y * wa.w + zv.z * wb.y + zv.w * wb.w;
    for (int off = 32; off; off >>= 1) {
        a0 += __shfl_down(a0, off, 64);
        a1 += __shfl_down(a1, off, 64);
    }
    if (lane == 0) {
        out[n * 2 + 0] = a0 + b2[0];
        out[n * 2 + 1] = a1 + b2[1];
    }
}

extern "C" void kernel_launch(void* const* d_in, const int* in_sizes, int n_in,
                              void* d_out, int out_size, void* d_ws, size_t ws_size,
                              hipStream_t stream) {
    const float* features = (const float*)d_in[0];
    const int* ei = (const int*)d_in[1];
    // d_in[2] = edgenet_input (bypassed by edge_weight_override)
    const float* ew = (const float*)d_in[3];
    const float* cheb_w = (const float*)d_in[4];
    const float* w1 = (const float*)d_in[5];
    const float* b1 = (const float*)d_in[6];
    const float* g = (const float*)d_in[7];
    const float* be = (const float*)d_in[8];
    const float* mn = (const float*)d_in[9];
    const float* vr = (const float*)d_in[10];
    const float* w2 = (const float*)d_in[11];
    const float* b2 = (const float*)d_in[12];
    float* out = (float*)d_out;  // [NN*2] logits, then [EE] ew

    char* p = (char*)d_ws;
    auto alloc = [&](size_t bytes) -> char* {
        char* r = p;
        p += (bytes + 255) & ~(size_t)255;
        return r;
    };
    float* deg = (float*)alloc((size_t)NN * 4);
    int* counts = (int*)alloc((size_t)(NN + 1) * 4);
    int* cursor = (int*)alloc((size_t)NN * 4);
    size_t zero_bytes = (size_t)(p - (char*)deg);
    int* offs = (int*)alloc((size_t)(NN + 1) * 4);
    int* srow = (int*)alloc((size_t)EE * 4);
    float* snorm = (float*)alloc((size_t)EE * 4);
    u16* xb = (u16*)alloc((size_t)NN * 256 * 2);
    u16* tx1 = (u16*)alloc((size_t)NN * 256 * 2);
    u16* tx2 = (u16*)alloc((size_t)NN * 256 * 2);
    float* z = (float*)tx1;  // overlay: z (N*256 f32) reuses tx1+tx2 (contiguous)
    u16* jk = (u16*)alloc((size_t)NN * 1024 * 2);
    u16* chebbf = (u16*)alloc((size_t)LGN * 3 * 256 * 256 * 2);
    u16* w1bf = (u16*)alloc((size_t)1024 * 256 * 2);
    float* sc = (float*)alloc(256 * 4);
    float* sh = (float*)alloc(256 * 4);

    hipMemsetAsync(deg, 0, zero_bytes, stream);
    k_edge1<<<(EE + 255) / 256, 256, 0, stream>>>(ei, ew, deg, counts, out + (size_t)NN * 2);
    k_rsqrt<<<(NN + 255) / 256, 256, 0, stream>>>(deg);
    k_scan<<<1, 1024, 0, stream>>>(counts, offs);
    k_scatter<<<(EE + 255) / 256, 256, 0, stream>>>(ei, ew, deg, offs, cursor, srow, snorm);
    k_cast<<<((NN * 256) + 255) / 256, 256, 0, stream>>>(features, xb, NN * 256);
    k_cast<<<((LGN * 3 * 256 * 256) + 255) / 256, 256, 0, stream>>>(cheb_w, chebbf,
                                                                    LGN * 3 * 256 * 256);
    k_cast<<<((1024 * 256) + 255) / 256, 256, 0, stream>>>(w1, w1bf, 1024 * 256);
    k_foldbn<<<1, 256, 0, stream>>>(g, be, mn, vr, sc, sh);

    for (int i = 0; i < LGN; i++) {
        const u16* x = (i == 0) ? xb : (jk + (size_t)(i - 1) * 256);
        int ldx = (i == 0) ? 256 : 1024;
        k_prop<<<NN, 256, 0, stream>>>(x, ldx, (const u16*)nullptr, 0, 0, tx1, 256, offs, srow,
                                       snorm);
        k_prop<<<NN, 256, 0, stream>>>(tx1, 256, x, ldx, 1, tx2, 256, offs, srow, snorm);
        k_gemm<<<dim3(313, 4), 256, 0, stream>>>(
            x, tx1, tx2, (const u16*)nullptr, ldx, 256, 256, 0, 768,
            chebbf + (size_t)i * 768 * 256, 0, jk + (size_t)i * 256, 1024, (float*)nullptr,
            (const float*)nullptr, (const float*)nullptr, (const float*)nullptr);
    }
    k_gemm<<<dim3(313, 4), 256, 0, stream>>>(jk, jk + 256, jk + 512, jk + 768, 1024, 1024, 1024,
                                             1024, 1024, w1bf, 1, (u16*)nullptr, 0, z, b1, sc, sh);
    k_final<<<5000, 256, 0, stream>>>(z, w2, b2, out);
}